// Round 10
// baseline (2046.331 us; speedup 1.0000x reference)
//
#include <hip/hip_runtime.h>
#include <hip/hip_bf16.h>
#include <hip/hip_cooperative_groups.h>

namespace cg = cooperative_groups;

using bf16 = __hip_bfloat16;
typedef __attribute__((ext_vector_type(8))) short short8;
typedef __attribute__((ext_vector_type(4))) float f32x4;

// Problem constants
static constexpr int LB = 2;           // batch
static constexpr int LL = 1024;        // seq len
static constexpr int DM = 512;         // d_model
static constexpr int DI = 1024;        // d_inner
static constexpr int DSN = 16;         // d_state
static constexpr int RK = 32;          // dt_rank
static constexpr int MR_ROWS = LB * LL; // 2048 rows

static constexpr int NCHUNK = 64;      // time chunks per sequence
static constexpr int CH = LL / NCHUNK; // 16 steps per chunk

// ---------------------------------------------------------------------------
// async global->LDS, 16B per lane. LDS dest is wave-uniform base + lane*16.
// ---------------------------------------------------------------------------
__device__ __forceinline__ void gload16(const void* g, void* l) {
    __builtin_amdgcn_global_load_lds(
        (__attribute__((address_space(1))) void*)(g),
        (__attribute__((address_space(3))) void*)(l), 16, 0, 0);
}

// ---------------------------------------------------------------------------
// fp32 -> bf16 conversion, multi-segment in one launch
// ---------------------------------------------------------------------------
struct ConvArgs {
    const float* src[9];
    bf16*        dst[9];
    int          n4[9];
};

__global__ __launch_bounds__(256) void convert_bf16_multi(ConvArgs a) {
    const int s = blockIdx.y;
    const float4* __restrict__ src = (const float4*)a.src[s];
    bf16* __restrict__ dst = a.dst[s];
    const int n4 = a.n4[s];
    for (int i = blockIdx.x * 256 + threadIdx.x; i < n4; i += gridDim.x * 256) {
        float4 v = src[i];
        bf16 t[4] = {__float2bfloat16(v.x), __float2bfloat16(v.y),
                     __float2bfloat16(v.z), __float2bfloat16(v.w)};
        *(uint2*)(dst + (size_t)i * 4) = *(uint2*)t;
    }
}

// ---------------------------------------------------------------------------
// dtw transpose: out[layer][k][c] = in[layer][c][k]  (fp32, one-time, small)
// ---------------------------------------------------------------------------
__global__ __launch_bounds__(256) void transpose_dtw(const float* __restrict__ enc_dtw,
                                                     const float* __restrict__ prd_dtw,
                                                     float* __restrict__ out) {
    const int layer = blockIdx.y;
    const float* src = (layer < 4) ? enc_dtw + (size_t)layer * DI * RK
                                   : prd_dtw + (size_t)(layer - 4) * DI * RK;
    float* dst = out + (size_t)layer * RK * DI;
    const int idx = blockIdx.x * 256 + threadIdx.x; // over RK*DI
    const int k = idx >> 10, c = idx & (DI - 1);
    dst[idx] = src[(size_t)c * RK + k];
}

// ---------------------------------------------------------------------------
// LayerNorm over last dim (512). Wave-per-row: block = 4 waves = 4 rows.
// ---------------------------------------------------------------------------
__device__ __forceinline__ void ln_store8(float* outrow, int lane,
                                          const float* v) {
    float4 a = {v[0], v[1], v[2], v[3]}, b = {v[4], v[5], v[6], v[7]};
    ((float4*)outrow)[lane] = a;
    ((float4*)outrow)[lane + 64] = b;
}
__device__ __forceinline__ void ln_store8(bf16* outrow, int lane,
                                          const float* v) {
    bf16 t0[4] = {__float2bfloat16(v[0]), __float2bfloat16(v[1]),
                  __float2bfloat16(v[2]), __float2bfloat16(v[3])};
    bf16 t1[4] = {__float2bfloat16(v[4]), __float2bfloat16(v[5]),
                  __float2bfloat16(v[6]), __float2bfloat16(v[7])};
    ((uint2*)outrow)[lane] = *(uint2*)t0;
    ((uint2*)outrow)[lane + 64] = *(uint2*)t1;
}

template <typename T>
__global__ __launch_bounds__(256) void ln_kernel(const float* __restrict__ x,
                                                 const float* __restrict__ w,
                                                 const float* __restrict__ b,
                                                 T* __restrict__ out) {
    const int wid = threadIdx.x >> 6, lane = threadIdx.x & 63;
    const int row = blockIdx.x * 4 + wid;
    const float4* xr = (const float4*)(x + (size_t)row * DM);
    const float4 v0 = xr[lane], v1 = xr[lane + 64];

    float s = (v0.x + v0.y + v0.z + v0.w) + (v1.x + v1.y + v1.z + v1.w);
#pragma unroll
    for (int m = 1; m < 64; m <<= 1) s += __shfl_xor(s, m);
    const float mean = s * (1.f / DM);

    float d[8] = {v0.x - mean, v0.y - mean, v0.z - mean, v0.w - mean,
                  v1.x - mean, v1.y - mean, v1.z - mean, v1.w - mean};
    float s2 = 0.f;
#pragma unroll
    for (int q = 0; q < 8; ++q) s2 += d[q] * d[q];
#pragma unroll
    for (int m = 1; m < 64; m <<= 1) s2 += __shfl_xor(s2, m);
    const float rs = rsqrtf(s2 * (1.f / DM) + 1e-5f);

    const float4 w0 = ((const float4*)w)[lane], w1 = ((const float4*)w)[lane + 64];
    const float4 b0 = ((const float4*)b)[lane], b1 = ((const float4*)b)[lane + 64];
    float o[8] = {d[0] * rs * w0.x + b0.x, d[1] * rs * w0.y + b0.y,
                  d[2] * rs * w0.z + b0.z, d[3] * rs * w0.w + b0.w,
                  d[4] * rs * w1.x + b1.x, d[5] * rs * w1.y + b1.y,
                  d[6] * rs * w1.z + b1.z, d[7] * rs * w1.w + b1.w};
    ln_store8(out + (size_t)row * DM, lane, o);
}

// ---------------------------------------------------------------------------
// GEMM: C[M,N] = A[M,K] * B[N,K]^T  (A,B bf16 row-major K-contiguous)
// EPI: 1 = +bias[col] (fp32 C), 3 = += existing C (residual), 4 = bf16 C out.
// Staging via global_load_lds(16B): linear LDS dest, PRE-SWIZZLED global
// source; swizzled ds_read (rule #21).
// ---------------------------------------------------------------------------
template <int BM, int BN, int BK, int EPI>
__global__ __launch_bounds__(256) void gemm_bt(const bf16* __restrict__ A, int lda,
                                               const bf16* __restrict__ B, int ldb,
                                               float* __restrict__ C, int ldc,
                                               int K, const float* __restrict__ bias) {
    static_assert(BK == 64, "layout assumes 128B LDS row");
    static_assert(BM % 32 == 0 && BN % 32 == 0, "wave staging granularity");
    constexpr int MR = (BM / 2) / 16;
    constexpr int NR = (BN / 2) / 16;
    __shared__ __align__(16) char sA[BM * 128];
    __shared__ __align__(16) char sB[BN * 128];

    const int tid = threadIdx.x;
    const int lane = tid & 63, wid = tid >> 6;
    const int wr = wid >> 1, wc = wid & 1;
    const int m0 = blockIdx.y * BM, n0 = blockIdx.x * BN;

    f32x4 acc[MR][NR] = {};

    // per-lane staging source (pre-swizzled)
    const int lrow = lane >> 3;               // 0..7
    const int lcol = (lane & 7) ^ lrow;       // swizzled 16B block
    const size_t lda2 = (size_t)lda * 2, ldb2 = (size_t)ldb * 2;
    const char* Ab = (const char*)A + (size_t)(m0 + wid * (BM / 4) + lrow) * lda2
                     + lcol * 16;
    const char* Bb = (const char*)B + (size_t)(n0 + wid * (BN / 4) + lrow) * ldb2
                     + lcol * 16;
    char* sAw = sA + wid * (BM / 4) * 128;
    char* sBw = sB + wid * (BN / 4) * 128;

    for (int k0 = 0; k0 < K; k0 += BK) {
#pragma unroll
        for (int i = 0; i < BM / 32; ++i)
            gload16(Ab + (size_t)i * 8 * lda2 + (size_t)k0 * 2, sAw + i * 1024);
#pragma unroll
        for (int i = 0; i < BN / 32; ++i)
            gload16(Bb + (size_t)i * 8 * ldb2 + (size_t)k0 * 2, sBw + i * 1024);
        __syncthreads();
#pragma unroll
        for (int kk = 0; kk < BK; kk += 32) {
            const int kb2 = (kk + (lane >> 4) * 8) * 2; // byte col, 16B aligned
            short8 af[MR], bfr[NR];
#pragma unroll
            for (int m = 0; m < MR; ++m) {
                const int r = wr * (BM / 2) + m * 16 + (lane & 15);
                af[m] = *(const short8*)(sA + r * 128 + (kb2 ^ ((r & 7) << 4)));
            }
#pragma unroll
            for (int n = 0; n < NR; ++n) {
                const int r = wc * (BN / 2) + n * 16 + (lane & 15);
                bfr[n] = *(const short8*)(sB + r * 128 + (kb2 ^ ((r & 7) << 4)));
            }
#pragma unroll
            for (int m = 0; m < MR; ++m) {
#pragma unroll
                for (int n = 0; n < NR; ++n) {
                    acc[m][n] = __builtin_amdgcn_mfma_f32_16x16x32_bf16(af[m], bfr[n], acc[m][n], 0, 0, 0);
                }
            }
        }
        __syncthreads();
    }

#pragma unroll
    for (int m = 0; m < MR; ++m) {
#pragma unroll
        for (int n = 0; n < NR; ++n) {
            const int col = n0 + wc * (BN / 2) + n * 16 + (lane & 15);
            const float bv = (EPI == 1) ? bias[col] : 0.f;
#pragma unroll
            for (int j = 0; j < 4; ++j) {
                const int row = m0 + wr * (BM / 2) + m * 16 + (lane >> 4) * 4 + j;
                float v = acc[m][n][j] + bv;
                if (EPI == 4) {
                    ((bf16*)C)[(size_t)row * ldc + col] = __float2bfloat16(v);
                } else {
                    float* p = C + (size_t)row * ldc + col;
                    if (EPI == 3) v += *p;
                    *p = v;
                }
            }
        }
    }
}

// ---------------------------------------------------------------------------
// Cooperative mega-kernel: conv+silu -> xc_bf (+zero dbc) | grid.sync |
// xp-GEMM (MFMA, split-K x4 atomics, r6-proven count) | grid.sync |
// scan part1 | grid.sync | combine | grid.sync | scan part3.
// Grid MUST be 512 blocks x 256 threads (2 blocks/CU co-resident).
// ---------------------------------------------------------------------------
__global__ __launch_bounds__(256, 2) void mamba_inner(
    const bf16* __restrict__ xzb, const float* __restrict__ cw,
    const float* __restrict__ cb, const bf16* __restrict__ xpw,
    bf16* __restrict__ xc_bf, float* __restrict__ dbc,
    const float* __restrict__ Alog, const float* __restrict__ dtw_t,
    const float* __restrict__ dtb, const float* __restrict__ Dp,
    float* __restrict__ psum, float* __restrict__ ssum,
    bf16* __restrict__ yg) {
    cg::grid_group grid = cg::this_grid();
    const int bid = blockIdx.x;
    const int tid = threadIdx.x;
    const int lane = tid & 63, wid = tid >> 6;

    __shared__ __align__(16) char sA[16 * 128]; // 2KB (xp-GEMM A tile)
    __shared__ __align__(16) char sB[64 * 128]; // 8KB (xp-GEMM B tile)

    // ---- P1: conv(K=4)+SiLU -> xc_bf ; zero dbc ----
    {
        if (bid < 128) {
            ((float4*)dbc)[bid * 256 + tid] = make_float4(0.f, 0.f, 0.f, 0.f);
        }
        const int base = bid * 256 + tid;       // 131072 threads
        const int c = base & (DI - 1);
        const int r00 = base >> 10;             // rows r00, r00+128, ...
        const float4 w = *(const float4*)(cw + (size_t)c * 4);
        const float cbv = cb[c];
#pragma unroll
        for (int i = 0; i < 16; ++i) {
            const int r = r00 + i * 128;
            const int l = r & (LL - 1);
            const bf16* xi = xzb + (size_t)r * (2 * DI) + c;
            float acc = cbv + w.w * __bfloat162float(xi[0]);
            if (l >= 1) acc += w.z * __bfloat162float(xi[-(2 * DI)]);
            if (l >= 2) acc += w.y * __bfloat162float(xi[-(4 * DI)]);
            if (l >= 3) acc += w.x * __bfloat162float(xi[-(6 * DI)]);
            const float s = acc / (1.f + expf(-acc));
            xc_bf[(size_t)r * DI + c] = __float2bfloat16(s);
        }
    }
    grid.sync();

    // ---- P2: dbc += xc @ xpw^T (BM=16, BN=64, 128 M-tiles x 4 K-chunks) ----
    {
        const int mt = bid & 127, kc = bid >> 7;
        const int m0 = mt * 16;
        const int kbase = kc * 256;
        const int lrow = lane >> 3, lcol8 = lane & 7;
        f32x4 acc = {};
        for (int k0 = kbase; k0 < kbase + 256; k0 += 64) {
            if (wid == 0) {
#pragma unroll
                for (int i = 0; i < 2; ++i) {
                    const int ri = i * 8 + lrow;       // ri & 7 == lrow
                    const int ci = lcol8 ^ lrow;
                    gload16((const char*)xc_bf + (size_t)(m0 + ri) * (DI * 2)
                                + (size_t)k0 * 2 + ci * 16,
                            sA + i * 1024);
                }
            }
#pragma unroll
            for (int i = 0; i < 2; ++i) {
                const int ri = wid * 16 + i * 8 + lrow; // ri & 7 == lrow
                const int ci = lcol8 ^ lrow;
                gload16((const char*)xpw + (size_t)ri * (DI * 2)
                            + (size_t)k0 * 2 + ci * 16,
                        sB + (wid * 16 + i * 8) * 128);
            }
            __syncthreads();
#pragma unroll
            for (int kk = 0; kk < 64; kk += 32) {
                const int kb2 = (kk + (lane >> 4) * 8) * 2;
                const int ra = lane & 15;
                const short8 af = *(const short8*)(sA + ra * 128 + (kb2 ^ ((ra & 7) << 4)));
                const int rb = wid * 16 + (lane & 15);
                const short8 bfr = *(const short8*)(sB + rb * 128 + (kb2 ^ ((rb & 7) << 4)));
                acc = __builtin_amdgcn_mfma_f32_16x16x32_bf16(af, bfr, acc, 0, 0, 0);
            }
            __syncthreads();
        }
        const int col = wid * 16 + (lane & 15);
#pragma unroll
        for (int j = 0; j < 4; ++j) {
            const int row = m0 + (lane >> 4) * 4 + j;
            atomicAdd(&dbc[(size_t)row * 64 + col], acc[j]);
        }
    }
    grid.sync();

    // ---- P3: scan part1 (P, S per chunk; delta recomputed inline) ----
    {
        const int cb_ = bid & 15, cg_ = (bid >> 4) & 15, b = bid >> 8;
        const int c = cb_ * 64 + lane;
        const int chunk = cg_ * 4 + wid;
        const int r0 = b * LL + chunk * CH;

        float wv[RK];
#pragma unroll
        for (int k = 0; k < RK; ++k) wv[k] = dtw_t[(size_t)k * DI + c];
        const float bdt = dtb[c];

        float a2[DSN];
#pragma unroll
        for (int q = 0; q < 4; ++q) {
            const float4 al = *(const float4*)(Alog + (size_t)c * DSN + q * 4);
            a2[q * 4 + 0] = -expf(al.x) * 1.44269504f;
            a2[q * 4 + 1] = -expf(al.y) * 1.44269504f;
            a2[q * 4 + 2] = -expf(al.z) * 1.44269504f;
            a2[q * 4 + 3] = -expf(al.w) * 1.44269504f;
        }

        float h[DSN], P[DSN];
#pragma unroll
        for (int n = 0; n < DSN; ++n) { h[n] = 0.f; P[n] = 1.f; }

        for (int t = 0; t < CH; ++t) {
            const size_t r = r0 + t;
            float acc = bdt;
#pragma unroll
            for (int q = 0; q < RK / 4; ++q) {
                const float4 d4 = *(const float4*)(dbc + r * 64 + q * 4);
                acc = fmaf(d4.x, wv[q * 4 + 0], acc);
                acc = fmaf(d4.y, wv[q * 4 + 1], acc);
                acc = fmaf(d4.z, wv[q * 4 + 2], acc);
                acc = fmaf(d4.w, wv[q * 4 + 3], acc);
            }
            const float d = (acc > 20.f) ? acc : log1pf(expf(acc));
            const float xv = __bfloat162float(xc_bf[r * DI + c]);
            const float dxv = d * xv;
            float Bv[DSN];
#pragma unroll
            for (int q = 0; q < 4; ++q)
                *(float4*)&Bv[q * 4] = *(const float4*)(dbc + r * 64 + 32 + q * 4);
#pragma unroll
            for (int n = 0; n < DSN; ++n) {
                const float dA = exp2f(d * a2[n]);
                h[n] = fmaf(dA, h[n], dxv * Bv[n]);
                P[n] *= dA;
            }
        }

        const size_t obase = ((size_t)(b * NCHUNK + chunk) * DSN) * DI + c;
#pragma unroll
        for (int n = 0; n < DSN; ++n) {
            psum[obase + (size_t)n * DI] = P[n];
            ssum[obase + (size_t)n * DI] = h[n];
        }
    }
    grid.sync();

    // ---- P4: combine across chunks (blocks 0..127) ----
    if (bid < 128) {
        const int cb_ = bid & 15, grp = bid >> 4;
        const int idx = grp * 4 + wid; // [0,32): b*16+n
        const int b = idx >> 4, n = idx & 15;
        const int c = cb_ * 64 + lane;
        const size_t base = ((size_t)(b * NCHUNK) * DSN + n) * DI + c;
        const size_t stride = (size_t)DSN * DI;

        float h = 0.f;
        for (int j0 = 0; j0 < NCHUNK; j0 += 8) {
            float Pv[8], Sv[8];
#pragma unroll
            for (int u = 0; u < 8; ++u) {
                Pv[u] = psum[base + (j0 + u) * stride];
                Sv[u] = ssum[base + (j0 + u) * stride];
            }
#pragma unroll
            for (int u = 0; u < 8; ++u) {
                psum[base + (j0 + u) * stride] = h;
                h = fmaf(Pv[u], h, Sv[u]);
            }
        }
    }
    grid.sync();

    // ---- P5: scan part3 (re-scan from h_in, gate, store bf16) ----
    {
        const int cb_ = bid & 15, cg_ = (bid >> 4) & 15, b = bid >> 8;
        const int c = cb_ * 64 + lane;
        const int chunk = cg_ * 4 + wid;
        const int r0 = b * LL + chunk * CH;

        float wv[RK];
#pragma unroll
        for (int k = 0; k < RK; ++k) wv[k] = dtw_t[(size_t)k * DI + c];
        const float bdt = dtb[c];

        float a2[DSN];
#pragma unroll
        for (int q = 0; q < 4; ++q) {
            const float4 al = *(const float4*)(Alog + (size_t)c * DSN + q * 4);
            a2[q * 4 + 0] = -expf(al.x) * 1.44269504f;
            a2[q * 4 + 1] = -expf(al.y) * 1.44269504f;
            a2[q * 4 + 2] = -expf(al.z) * 1.44269504f;
            a2[q * 4 + 3] = -expf(al.w) * 1.44269504f;
        }
        const float dp = Dp[c];

        float h[DSN];
        const size_t hbase = ((size_t)(b * NCHUNK + chunk) * DSN) * DI + c;
#pragma unroll
        for (int n = 0; n < DSN; ++n) h[n] = psum[hbase + (size_t)n * DI];

        for (int t = 0; t < CH; ++t) {
            const size_t r = r0 + t;
            float acc = bdt;
#pragma unroll
            for (int q = 0; q < RK / 4; ++q) {
                const float4 d4 = *(const float4*)(dbc + r * 64 + q * 4);
                acc = fmaf(d4.x, wv[q * 4 + 0], acc);
                acc = fmaf(d4.y, wv[q * 4 + 1], acc);
                acc = fmaf(d4.z, wv[q * 4 + 2], acc);
                acc = fmaf(d4.w, wv[q * 4 + 3], acc);
            }
            const float d = (acc > 20.f) ? acc : log1pf(expf(acc));
            const float xv = __bfloat162float(xc_bf[r * DI + c]);
            const float zv = __bfloat162float(xzb[r * (2 * DI) + DI + c]);
            const float dxv = d * xv;
            float Bv[DSN], Cv[DSN];
#pragma unroll
            for (int q = 0; q < 4; ++q) {
                *(float4*)&Bv[q * 4] = *(const float4*)(dbc + r * 64 + 32 + q * 4);
                *(float4*)&Cv[q * 4] = *(const float4*)(dbc + r * 64 + 48 + q * 4);
            }
            float y0 = 0.f, y1 = 0.f, y2 = 0.f, y3 = 0.f;
#pragma unroll
            for (int q = 0; q < 4; ++q) {
                {
                    const float dA = exp2f(d * a2[q * 4 + 0]);
                    h[q * 4 + 0] = fmaf(dA, h[q * 4 + 0], dxv * Bv[q * 4 + 0]);
                    y0 = fmaf(h[q * 4 + 0], Cv[q * 4 + 0], y0);
                }
                {
                    const float dA = exp2f(d * a2[q * 4 + 1]);
                    h[q * 4 + 1] = fmaf(dA, h[q * 4 + 1], dxv * Bv[q * 4 + 1]);
                    y1 = fmaf(h[q * 4 + 1], Cv[q * 4 + 1], y1);
                }
                {
                    const float dA = exp2f(d * a2[q * 4 + 2]);
                    h[q * 4 + 2] = fmaf(dA, h[q * 4 + 2], dxv * Bv[q * 4 + 2]);
                    y2 = fmaf(h[q * 4 + 2], Cv[q * 4 + 2], y2);
                }
                {
                    const float dA = exp2f(d * a2[q * 4 + 3]);
                    h[q * 4 + 3] = fmaf(dA, h[q * 4 + 3], dxv * Bv[q * 4 + 3]);
                    y3 = fmaf(h[q * 4 + 3], Cv[q * 4 + 3], y3);
                }
            }
            const float y = (y0 + y1) + (y2 + y3);
            const float zs = zv / (1.f + expf(-zv));
            yg[r * DI + c] = __float2bfloat16((y + dp * xv) * zs);
        }
    }
}

// ---------------------------------------------------------------------------
// One Mamba layer (4 dispatches)
// ---------------------------------------------------------------------------
static void run_mamba_layer(hipStream_t stream, float* resid,
                            const float* ln_w, const float* ln_b,
                            const bf16* inw_bf,
                            const float* conv_w, const float* conv_b,
                            const bf16* xpw_bf,
                            const float* dtw_t, const float* dt_b,
                            const float* Alog, const float* Dp,
                            const bf16* outw_bf,
                            bf16* ln_bf, bf16* xzb, bf16* xc_bf, float* dbc,
                            float* psum, float* ssum, bf16* yg_bf) {
    ln_kernel<bf16><<<MR_ROWS / 4, 256, 0, stream>>>(resid, ln_w, ln_b, ln_bf);
    // xz = ln_out @ in_w^T : M=2048, N=2048, K=512 -> bf16 output
    gemm_bt<64, 64, 64, 4><<<dim3(2 * DI / 64, MR_ROWS / 64), 256, 0, stream>>>(
        ln_bf, DM, inw_bf, DM, (float*)xzb, 2 * DI, DM, nullptr);
    // cooperative: conv+silu | xp-GEMM | scan1 | combine | scan3
    void* args[] = {(void*)&xzb, (void*)&conv_w, (void*)&conv_b, (void*)&xpw_bf,
                    (void*)&xc_bf, (void*)&dbc, (void*)&Alog, (void*)&dtw_t,
                    (void*)&dt_b, (void*)&Dp, (void*)&psum, (void*)&ssum,
                    (void*)&yg_bf};
    hipLaunchCooperativeKernel(reinterpret_cast<void*>(mamba_inner),
                               dim3(512), dim3(256), args, 0, stream);
    // resid += yg @ out_w^T : M=2048, N=512, K=1024
    gemm_bt<32, 64, 64, 3><<<dim3(DM / 64, MR_ROWS / 32), 256, 0, stream>>>(
        yg_bf, DI, outw_bf, DI, resid, DM, DI, nullptr);
}

// ---------------------------------------------------------------------------
extern "C" void kernel_launch(void* const* d_in, const int* in_sizes, int n_in,
                              void* d_out, int out_size, void* d_ws, size_t ws_size,
                              hipStream_t stream) {
    const float* x         = (const float*)d_in[0];
    const float* inp_w     = (const float*)d_in[1];
    const float* inp_b     = (const float*)d_in[2];
    const float* enc_ln_w  = (const float*)d_in[3];
    const float* enc_ln_b  = (const float*)d_in[4];
    const float* enc_in_w  = (const float*)d_in[5];
    const float* enc_conv_w= (const float*)d_in[6];
    const float* enc_conv_b= (const float*)d_in[7];
    const float* enc_xp_w  = (const float*)d_in[8];
    const float* enc_dt_w  = (const float*)d_in[9];
    const float* enc_dt_b  = (const float*)d_in[10];
    const float* enc_Alog  = (const float*)d_in[11];
    const float* enc_D     = (const float*)d_in[12];
    const float* enc_out_w = (const float*)d_in[13];
    const float* fin_ln_w  = (const float*)d_in[14];
    const float* fin_ln_b  = (const float*)d_in[15];
    const float* prd_ln_w  = (const float*)d_in[16];
    const float* prd_ln_b  = (const float*)d_in[17];
    const float* prd_in_w  = (const float*)d_in[18];
    const float* prd_conv_w= (const float*)d_in[19];
    const float* prd_conv_b= (const float*)d_in[20];
    const float* prd_xp_w  = (const float*)d_in[21];
    const float* prd_dt_w  = (const float*)d_in[22];
    const float* prd_dt_b  = (const float*)d_in[23];
    const float* prd_Alog  = (const float*)d_in[24];
    const float* prd_D     = (const float*)d_in[25];
    const float* prd_out_w = (const float*)d_in[26];
    const float* prd_nrm_w = (const float*)d_in[27];
    const float* prd_nrm_b = (const float*)d_in[28];
    const float* prd_proj_w= (const float*)d_in[29];
    const float* prd_proj_b= (const float*)d_in[30];

    char* wp = (char*)d_ws;
    auto carve = [&](size_t elems, size_t esz) {
        void* p = (void*)wp;
        wp += (elems * esz + 255) & ~(size_t)255;
        return p;
    };
    bf16* x_bf     = (bf16*)carve((size_t)MR_ROWS * 128, 2);
    bf16* inpw_bf  = (bf16*)carve((size_t)DM * 128, 2);
    bf16* einw_bf  = (bf16*)carve(4ull * 2 * DI * DM, 2);
    bf16* expw_bf  = (bf16*)carve(4ull * 64 * DI, 2);
    bf16* eoutw_bf = (bf16*)carve(4ull * DM * DI, 2);
    bf16* pinw_bf  = (bf16*)carve(2ull * 2 * DI * DM, 2);
    bf16* pxpw_bf  = (bf16*)carve(2ull * 64 * DI, 2);
    bf16* poutw_bf = (bf16*)carve(2ull * DM * DI, 2);
    bf16* projw_bf = (bf16*)carve((size_t)DM * DM, 2);
    float* dtwt    = (float*)carve(6ull * RK * DI, 4);
    float* hbuf    = (float*)carve((size_t)MR_ROWS * DM, 4);
    float* pbuf    = (float*)carve((size_t)MR_ROWS * DM, 4);
    bf16* ln_bf    = (bf16*)carve((size_t)MR_ROWS * DM, 2);
    bf16* xzb      = (bf16*)carve((size_t)MR_ROWS * 2 * DI, 2);
    bf16* xc_bf    = (bf16*)carve((size_t)MR_ROWS * DI, 2);
    float* dbc     = (float*)carve((size_t)MR_ROWS * 64, 4);
    float* psum    = (float*)carve((size_t)LB * NCHUNK * DSN * DI, 4);
    float* ssum    = (float*)carve((size_t)LB * NCHUNK * DSN * DI, 4);
    bf16* yg_bf    = (bf16*)carve((size_t)MR_ROWS * DI, 2);

    // --- weight/input conversion to bf16 (one launch) + dtw transpose ---
    ConvArgs ca;
    const float* csrc[9] = {x, inp_w, enc_in_w, enc_xp_w, enc_out_w,
                            prd_in_w, prd_xp_w, prd_out_w, prd_proj_w};
    bf16* cdst[9] = {x_bf, inpw_bf, einw_bf, expw_bf, eoutw_bf,
                     pinw_bf, pxpw_bf, poutw_bf, projw_bf};
    const int cn[9] = {MR_ROWS * 128, DM * 128, 4 * 2 * DI * DM, 4 * 64 * DI, 4 * DM * DI,
                       2 * 2 * DI * DM, 2 * 64 * DI, 2 * DM * DI, DM * DM};
    for (int i = 0; i < 9; ++i) { ca.src[i] = csrc[i]; ca.dst[i] = cdst[i]; ca.n4[i] = cn[i] / 4; }
    convert_bf16_multi<<<dim3(128, 9), 256, 0, stream>>>(ca);
    transpose_dtw<<<dim3(RK * DI / 256, 6), 256, 0, stream>>>(enc_dt_w, prd_dt_w, dtwt);

    // --- input projection: h = x @ inp_w^T + inp_b  (M=2048, N=512, K=128) ---
    gemm_bt<32, 64, 64, 1><<<dim3(DM / 64, MR_ROWS / 32), 256, 0, stream>>>(
        x_bf, 128, inpw_bf, 128, hbuf, DM, 128, inp_b);

    // --- encoder layers ---
    for (int i = 0; i < 4; ++i) {
        run_mamba_layer(stream, hbuf,
                        enc_ln_w + (size_t)i * DM, enc_ln_b + (size_t)i * DM,
                        einw_bf + (size_t)i * 2 * DI * DM,
                        enc_conv_w + (size_t)i * DI * 4, enc_conv_b + (size_t)i * DI,
                        expw_bf + (size_t)i * 64 * DI,
                        dtwt + (size_t)i * RK * DI, enc_dt_b + (size_t)i * DI,
                        enc_Alog + (size_t)i * DI * DSN, enc_D + (size_t)i * DI,
                        eoutw_bf + (size_t)i * DM * DI,
                        ln_bf, xzb, xc_bf, dbc, psum, ssum, yg_bf);
    }

    // --- final encoder LN -> predictor stream ---
    ln_kernel<float><<<MR_ROWS / 4, 256, 0, stream>>>(hbuf, fin_ln_w, fin_ln_b, pbuf);

    // --- predictor layers ---
    for (int i = 0; i < 2; ++i) {
        run_mamba_layer(stream, pbuf,
                        prd_ln_w + (size_t)i * DM, prd_ln_b + (size_t)i * DM,
                        pinw_bf + (size_t)i * 2 * DI * DM,
                        prd_conv_w + (size_t)i * DI * 4, prd_conv_b + (size_t)i * DI,
                        pxpw_bf + (size_t)i * 64 * DI,
                        dtwt + (size_t)(4 + i) * RK * DI, prd_dt_b + (size_t)i * DI,
                        prd_Alog + (size_t)i * DI * DSN, prd_D + (size_t)i * DI,
                        poutw_bf + (size_t)i * DM * DI,
                        ln_bf, xzb, xc_bf, dbc, psum, ssum, yg_bf);
    }

    // --- final norm + projection ---
    ln_kernel<bf16><<<MR_ROWS / 4, 256, 0, stream>>>(pbuf, prd_nrm_w, prd_nrm_b, ln_bf);
    gemm_bt<32, 64, 64, 1><<<dim3(DM / 64, MR_ROWS / 32), 256, 0, stream>>>(
        ln_bf, DM, projw_bf, DM, (float*)d_out, DM, DM, prd_proj_b);

    (void)in_sizes; (void)n_in; (void)out_size; (void)ws_size;
}

// Round 11
// 693.849 us; speedup vs baseline: 2.9492x; 2.9492x over previous
//
#include <hip/hip_runtime.h>
#include <hip/hip_bf16.h>

using bf16 = __hip_bfloat16;
typedef __attribute__((ext_vector_type(8))) short short8;
typedef __attribute__((ext_vector_type(4))) float f32x4;

// Problem constants
static constexpr int LB = 2;           // batch
static constexpr int LL = 1024;        // seq len
static constexpr int DM = 512;         // d_model
static constexpr int DI = 1024;        // d_inner
static constexpr int DSN = 16;         // d_state
static constexpr int RK = 32;          // dt_rank
static constexpr int MR_ROWS = LB * LL; // 2048 rows

static constexpr int NCHUNK = 64;      // time chunks per sequence
static constexpr int CH = LL / NCHUNK; // 16 steps per chunk

// ---------------------------------------------------------------------------
// async global->LDS, 16B per lane. LDS dest is wave-uniform base + lane*16.
// ---------------------------------------------------------------------------
__device__ __forceinline__ void gload16(const void* g, void* l) {
    __builtin_amdgcn_global_load_lds(
        (__attribute__((address_space(1))) void*)(g),
        (__attribute__((address_space(3))) void*)(l), 16, 0, 0);
}

__device__ __forceinline__ float b2f(short v) {
    union { unsigned int u; float f; } cvt;
    cvt.u = ((unsigned int)(unsigned short)v) << 16;
    return cvt.f;
}

// ---------------------------------------------------------------------------
// fp32 -> bf16 conversion, multi-segment in one launch
// ---------------------------------------------------------------------------
struct ConvArgs {
    const float* src[9];
    bf16*        dst[9];
    int          n4[9];
};

__global__ __launch_bounds__(256) void convert_bf16_multi(ConvArgs a) {
    const int s = blockIdx.y;
    const float4* __restrict__ src = (const float4*)a.src[s];
    bf16* __restrict__ dst = a.dst[s];
    const int n4 = a.n4[s];
    for (int i = blockIdx.x * 256 + threadIdx.x; i < n4; i += gridDim.x * 256) {
        float4 v = src[i];
        bf16 t[4] = {__float2bfloat16(v.x), __float2bfloat16(v.y),
                     __float2bfloat16(v.z), __float2bfloat16(v.w)};
        *(uint2*)(dst + (size_t)i * 4) = *(uint2*)t;
    }
}

// ---------------------------------------------------------------------------
// dtw transpose: out[layer][k][c] = in[layer][c][k]  (fp32, one-time, small)
// ---------------------------------------------------------------------------
__global__ __launch_bounds__(256) void transpose_dtw(const float* __restrict__ enc_dtw,
                                                     const float* __restrict__ prd_dtw,
                                                     float* __restrict__ out) {
    const int layer = blockIdx.y;
    const float* src = (layer < 4) ? enc_dtw + (size_t)layer * DI * RK
                                   : prd_dtw + (size_t)(layer - 4) * DI * RK;
    float* dst = out + (size_t)layer * RK * DI;
    const int idx = blockIdx.x * 256 + threadIdx.x; // over RK*DI
    const int k = idx >> 10, c = idx & (DI - 1);
    dst[idx] = src[(size_t)c * RK + k];
}

// ---------------------------------------------------------------------------
// LayerNorm over last dim (512). Wave-per-row: block = 4 waves = 4 rows,
// grid 512. Wave-local shuffle reduce only. Optionally zeroes dbc.
// ---------------------------------------------------------------------------
__device__ __forceinline__ void ln_store8(float* outrow, int lane,
                                          const float* v) {
    float4 a = {v[0], v[1], v[2], v[3]}, b = {v[4], v[5], v[6], v[7]};
    ((float4*)outrow)[lane] = a;
    ((float4*)outrow)[lane + 64] = b;
}
__device__ __forceinline__ void ln_store8(bf16* outrow, int lane,
                                          const float* v) {
    bf16 t0[4] = {__float2bfloat16(v[0]), __float2bfloat16(v[1]),
                  __float2bfloat16(v[2]), __float2bfloat16(v[3])};
    bf16 t1[4] = {__float2bfloat16(v[4]), __float2bfloat16(v[5]),
                  __float2bfloat16(v[6]), __float2bfloat16(v[7])};
    ((uint2*)outrow)[lane] = *(uint2*)t0;
    ((uint2*)outrow)[lane + 64] = *(uint2*)t1;
}

template <typename T>
__global__ __launch_bounds__(256) void ln_kernel(const float* __restrict__ x,
                                                 const float* __restrict__ w,
                                                 const float* __restrict__ b,
                                                 T* __restrict__ out,
                                                 float* __restrict__ dbc_zero) {
    if (dbc_zero != nullptr && blockIdx.x < 128) {
        ((float4*)dbc_zero)[blockIdx.x * 256 + threadIdx.x] =
            make_float4(0.f, 0.f, 0.f, 0.f);
    }
    const int wid = threadIdx.x >> 6, lane = threadIdx.x & 63;
    const int row = blockIdx.x * 4 + wid;
    const float4* xr = (const float4*)(x + (size_t)row * DM);
    const float4 v0 = xr[lane], v1 = xr[lane + 64];

    float s = (v0.x + v0.y + v0.z + v0.w) + (v1.x + v1.y + v1.z + v1.w);
#pragma unroll
    for (int m = 1; m < 64; m <<= 1) s += __shfl_xor(s, m);
    const float mean = s * (1.f / DM);

    float d[8] = {v0.x - mean, v0.y - mean, v0.z - mean, v0.w - mean,
                  v1.x - mean, v1.y - mean, v1.z - mean, v1.w - mean};
    float s2 = 0.f;
#pragma unroll
    for (int q = 0; q < 8; ++q) s2 += d[q] * d[q];
#pragma unroll
    for (int m = 1; m < 64; m <<= 1) s2 += __shfl_xor(s2, m);
    const float rs = rsqrtf(s2 * (1.f / DM) + 1e-5f);

    const float4 w0 = ((const float4*)w)[lane], w1 = ((const float4*)w)[lane + 64];
    const float4 b0 = ((const float4*)b)[lane], b1 = ((const float4*)b)[lane + 64];
    float o[8] = {d[0] * rs * w0.x + b0.x, d[1] * rs * w0.y + b0.y,
                  d[2] * rs * w0.z + b0.z, d[3] * rs * w0.w + b0.w,
                  d[4] * rs * w1.x + b1.x, d[5] * rs * w1.y + b1.y,
                  d[6] * rs * w1.z + b1.z, d[7] * rs * w1.w + b1.w};
    ln_store8(out + (size_t)row * DM, lane, o);
}

// ---------------------------------------------------------------------------
// GEMM: C[M,N] = A[M,K] * B[N,K]^T  (A,B bf16 row-major K-contiguous)
// EPI: 1 = +bias[col] (fp32 C), 2 = atomicAdd split-K over blockIdx.z
//      (K arg = per-chunk K), 3 = += existing C (residual), 4 = bf16 C out.
// Staging via global_load_lds(16B): linear LDS dest, PRE-SWIZZLED global
// source; swizzled ds_read (rule #21).
// ---------------------------------------------------------------------------
template <int BM, int BN, int BK, int EPI>
__global__ __launch_bounds__(256) void gemm_bt(const bf16* __restrict__ A, int lda,
                                               const bf16* __restrict__ B, int ldb,
                                               float* __restrict__ C, int ldc,
                                               int K, const float* __restrict__ bias) {
    static_assert(BK == 64, "layout assumes 128B LDS row");
    static_assert(BM % 32 == 0 && BN % 32 == 0, "wave staging granularity");
    constexpr int MR = (BM / 2) / 16;
    constexpr int NR = (BN / 2) / 16;
    __shared__ __align__(16) char sA[BM * 128];
    __shared__ __align__(16) char sB[BN * 128];

    const int tid = threadIdx.x;
    const int lane = tid & 63, wid = tid >> 6;
    const int wr = wid >> 1, wc = wid & 1;
    const int m0 = blockIdx.y * BM, n0 = blockIdx.x * BN;
    const int kbase = (EPI == 2) ? blockIdx.z * K : 0;

    f32x4 acc[MR][NR] = {};

    // per-lane staging source (pre-swizzled)
    const int lrow = lane >> 3;               // 0..7
    const int lcol = (lane & 7) ^ lrow;       // swizzled 16B block
    const size_t lda2 = (size_t)lda * 2, ldb2 = (size_t)ldb * 2;
    const char* Ab = (const char*)A + (size_t)(m0 + wid * (BM / 4) + lrow) * lda2
                     + lcol * 16 + (size_t)kbase * 2;
    const char* Bb = (const char*)B + (size_t)(n0 + wid * (BN / 4) + lrow) * ldb2
                     + lcol * 16 + (size_t)kbase * 2;
    char* sAw = sA + wid * (BM / 4) * 128;
    char* sBw = sB + wid * (BN / 4) * 128;

    for (int k0 = 0; k0 < K; k0 += BK) {
#pragma unroll
        for (int i = 0; i < BM / 32; ++i)
            gload16(Ab + (size_t)i * 8 * lda2 + (size_t)k0 * 2, sAw + i * 1024);
#pragma unroll
        for (int i = 0; i < BN / 32; ++i)
            gload16(Bb + (size_t)i * 8 * ldb2 + (size_t)k0 * 2, sBw + i * 1024);
        __syncthreads();
#pragma unroll
        for (int kk = 0; kk < BK; kk += 32) {
            const int kb2 = (kk + (lane >> 4) * 8) * 2; // byte col, 16B aligned
            short8 af[MR], bfr[NR];
#pragma unroll
            for (int m = 0; m < MR; ++m) {
                const int r = wr * (BM / 2) + m * 16 + (lane & 15);
                af[m] = *(const short8*)(sA + r * 128 + (kb2 ^ ((r & 7) << 4)));
            }
#pragma unroll
            for (int n = 0; n < NR; ++n) {
                const int r = wc * (BN / 2) + n * 16 + (lane & 15);
                bfr[n] = *(const short8*)(sB + r * 128 + (kb2 ^ ((r & 7) << 4)));
            }
#pragma unroll
            for (int m = 0; m < MR; ++m) {
#pragma unroll
                for (int n = 0; n < NR; ++n) {
                    acc[m][n] = __builtin_amdgcn_mfma_f32_16x16x32_bf16(af[m], bfr[n], acc[m][n], 0, 0, 0);
                }
            }
        }
        __syncthreads();
    }

#pragma unroll
    for (int m = 0; m < MR; ++m) {
#pragma unroll
        for (int n = 0; n < NR; ++n) {
            const int col = n0 + wc * (BN / 2) + n * 16 + (lane & 15);
            const float bv = (EPI == 1) ? bias[col] : 0.f;
#pragma unroll
            for (int j = 0; j < 4; ++j) {
                const int row = m0 + wr * (BM / 2) + m * 16 + (lane >> 4) * 4 + j;
                float v = acc[m][n][j] + bv;
                if (EPI == 4) {
                    ((bf16*)C)[(size_t)row * ldc + col] = __float2bfloat16(v);
                } else {
                    float* p = C + (size_t)row * ldc + col;
                    if (EPI == 2) {
                        atomicAdd(p, v);
                    } else {
                        if (EPI == 3) v += *p;
                        *p = v;
                    }
                }
            }
        }
    }
}

// ---------------------------------------------------------------------------
// Causal depthwise conv (K=4) + SiLU, bf16 in/out, vectorized 8 ch/thread.
// ---------------------------------------------------------------------------
__global__ __launch_bounds__(256) void conv_silu_b(const bf16* __restrict__ xzb,
                                                   const float* __restrict__ cw,
                                                   const float* __restrict__ cb,
                                                   bf16* __restrict__ xc_bf) {
    const int idx = blockIdx.x * 256 + threadIdx.x; // over 2048*128 groups
    const int c8 = (idx & 127) * 8;
    const int r = idx >> 7;
    const int l = r & (LL - 1);
    const bf16* xi = xzb + (size_t)r * (2 * DI) + c8;
    const short8 zv8 = {};
    const short8 x0 = *(const short8*)xi;
    const short8 x1 = (l >= 1) ? *(const short8*)(xi - 2 * DI) : zv8;
    const short8 x2 = (l >= 2) ? *(const short8*)(xi - 4 * DI) : zv8;
    const short8 x3 = (l >= 3) ? *(const short8*)(xi - 6 * DI) : zv8;

    bf16 outv[8];
#pragma unroll
    for (int j = 0; j < 8; ++j) {
        const float4 w = *(const float4*)(cw + (size_t)(c8 + j) * 4);
        float acc = cb[c8 + j] + w.w * b2f(x0[j]) + w.z * b2f(x1[j])
                    + w.y * b2f(x2[j]) + w.x * b2f(x3[j]);
        const float s = acc / (1.f + expf(-acc)); // silu
        outv[j] = __float2bfloat16(s);
    }
    *(uint4*)(xc_bf + (size_t)r * DI + c8) = *(uint4*)outv;
}

// ---------------------------------------------------------------------------
// Selective scan, 3-kernel chunked form; channel in the LANE dimension.
// delta = softplus(dt @ dt_w^T + dt_b) computed inline in part1 AND
// recomputed bit-identically in part3 -> no delta buffer.
// ---------------------------------------------------------------------------
__global__ __launch_bounds__(256) void scan_part1(const bf16* __restrict__ xcb,
                                                  const float* __restrict__ dbc,
                                                  const float* __restrict__ Alog,
                                                  const float* __restrict__ dtw_t,
                                                  const float* __restrict__ dtb,
                                                  float* __restrict__ psum,
                                                  float* __restrict__ ssum) {
    const int lane = threadIdx.x & 63;
    const int wsub = threadIdx.x >> 6;
    const int c = blockIdx.x * 64 + lane;
    const int chunk = blockIdx.y * 4 + wsub;
    const int b = blockIdx.z;
    const int r0 = b * LL + chunk * CH;

    float wv[RK];
#pragma unroll
    for (int k = 0; k < RK; ++k) wv[k] = dtw_t[(size_t)k * DI + c];
    const float bdt = dtb[c];

    float a2[DSN];
#pragma unroll
    for (int q = 0; q < 4; ++q) {
        const float4 al = *(const float4*)(Alog + (size_t)c * DSN + q * 4);
        a2[q * 4 + 0] = -expf(al.x) * 1.44269504f;
        a2[q * 4 + 1] = -expf(al.y) * 1.44269504f;
        a2[q * 4 + 2] = -expf(al.z) * 1.44269504f;
        a2[q * 4 + 3] = -expf(al.w) * 1.44269504f;
    }

    float h[DSN], P[DSN];
#pragma unroll
    for (int n = 0; n < DSN; ++n) { h[n] = 0.f; P[n] = 1.f; }

    for (int t = 0; t < CH; ++t) {
        const size_t r = r0 + t;
        float acc = bdt;
#pragma unroll
        for (int q = 0; q < RK / 4; ++q) {
            const float4 d4 = *(const float4*)(dbc + r * 64 + q * 4);
            acc = fmaf(d4.x, wv[q * 4 + 0], acc);
            acc = fmaf(d4.y, wv[q * 4 + 1], acc);
            acc = fmaf(d4.z, wv[q * 4 + 2], acc);
            acc = fmaf(d4.w, wv[q * 4 + 3], acc);
        }
        const float d = (acc > 20.f) ? acc : log1pf(expf(acc));

        const float xv = __bfloat162float(xcb[r * DI + c]);
        const float dxv = d * xv;
        float Bv[DSN];
#pragma unroll
        for (int q = 0; q < 4; ++q)
            *(float4*)&Bv[q * 4] = *(const float4*)(dbc + r * 64 + 32 + q * 4);
#pragma unroll
        for (int n = 0; n < DSN; ++n) {
            const float dA = exp2f(d * a2[n]);
            h[n] = fmaf(dA, h[n], dxv * Bv[n]);
            P[n] *= dA;
        }
    }

    const size_t obase = ((size_t)(b * NCHUNK + chunk) * DSN) * DI + c;
#pragma unroll
    for (int n = 0; n < DSN; ++n) {
        psum[obase + (size_t)n * DI] = P[n];
        ssum[obase + (size_t)n * DI] = h[n];
    }
}

__global__ __launch_bounds__(256) void scan_combine(float* __restrict__ psum,
                                                    const float* __restrict__ ssum) {
    const int lane = threadIdx.x & 63;
    const int idx = blockIdx.y * 4 + (threadIdx.x >> 6); // [0,32): b*16+n
    const int b = idx >> 4, n = idx & 15;
    const int c = blockIdx.x * 64 + lane;
    const size_t base = ((size_t)(b * NCHUNK) * DSN + n) * DI + c;
    const size_t stride = (size_t)DSN * DI; // chunk stride

    float h = 0.f;
    for (int j0 = 0; j0 < NCHUNK; j0 += 8) {
        float Pv[8], Sv[8];
#pragma unroll
        for (int u = 0; u < 8; ++u) {
            Pv[u] = psum[base + (j0 + u) * stride];
            Sv[u] = ssum[base + (j0 + u) * stride];
        }
#pragma unroll
        for (int u = 0; u < 8; ++u) {
            psum[base + (j0 + u) * stride] = h; // h_in for chunk j0+u
            h = fmaf(Pv[u], h, Sv[u]);
        }
    }
}

__global__ __launch_bounds__(256) void scan_part3(const bf16* __restrict__ xcb,
                                                  const bf16* __restrict__ xzb,
                                                  const float* __restrict__ dbc,
                                                  const float* __restrict__ Alog,
                                                  const float* __restrict__ dtw_t,
                                                  const float* __restrict__ dtb,
                                                  const float* __restrict__ Dp,
                                                  const float* __restrict__ hin,
                                                  bf16* __restrict__ yg) {
    const int lane = threadIdx.x & 63;
    const int wsub = threadIdx.x >> 6;
    const int c = blockIdx.x * 64 + lane;
    const int chunk = blockIdx.y * 4 + wsub;
    const int b = blockIdx.z;
    const int r0 = b * LL + chunk * CH;

    float wv[RK];
#pragma unroll
    for (int k = 0; k < RK; ++k) wv[k] = dtw_t[(size_t)k * DI + c];
    const float bdt = dtb[c];

    float a2[DSN];
#pragma unroll
    for (int q = 0; q < 4; ++q) {
        const float4 al = *(const float4*)(Alog + (size_t)c * DSN + q * 4);
        a2[q * 4 + 0] = -expf(al.x) * 1.44269504f;
        a2[q * 4 + 1] = -expf(al.y) * 1.44269504f;
        a2[q * 4 + 2] = -expf(al.z) * 1.44269504f;
        a2[q * 4 + 3] = -expf(al.w) * 1.44269504f;
    }
    const float dp = Dp[c];

    float h[DSN];
    const size_t hbase = ((size_t)(b * NCHUNK + chunk) * DSN) * DI + c;
#pragma unroll
    for (int n = 0; n < DSN; ++n) h[n] = hin[hbase + (size_t)n * DI];

    for (int t = 0; t < CH; ++t) {
        const size_t r = r0 + t;
        float acc = bdt;
#pragma unroll
        for (int q = 0; q < RK / 4; ++q) {
            const float4 d4 = *(const float4*)(dbc + r * 64 + q * 4);
            acc = fmaf(d4.x, wv[q * 4 + 0], acc);
            acc = fmaf(d4.y, wv[q * 4 + 1], acc);
            acc = fmaf(d4.z, wv[q * 4 + 2], acc);
            acc = fmaf(d4.w, wv[q * 4 + 3], acc);
        }
        const float d = (acc > 20.f) ? acc : log1pf(expf(acc));

        const float xv = __bfloat162float(xcb[r * DI + c]);
        const float zv = __bfloat162float(xzb[r * (2 * DI) + DI + c]);
        const float dxv = d * xv;
        float Bv[DSN], Cv[DSN];
#pragma unroll
        for (int q = 0; q < 4; ++q) {
            *(float4*)&Bv[q * 4] = *(const float4*)(dbc + r * 64 + 32 + q * 4);
            *(float4*)&Cv[q * 4] = *(const float4*)(dbc + r * 64 + 48 + q * 4);
        }
        float y0 = 0.f, y1 = 0.f, y2 = 0.f, y3 = 0.f;
#pragma unroll
        for (int q = 0; q < 4; ++q) {
            {
                const float dA = exp2f(d * a2[q * 4 + 0]);
                h[q * 4 + 0] = fmaf(dA, h[q * 4 + 0], dxv * Bv[q * 4 + 0]);
                y0 = fmaf(h[q * 4 + 0], Cv[q * 4 + 0], y0);
            }
            {
                const float dA = exp2f(d * a2[q * 4 + 1]);
                h[q * 4 + 1] = fmaf(dA, h[q * 4 + 1], dxv * Bv[q * 4 + 1]);
                y1 = fmaf(h[q * 4 + 1], Cv[q * 4 + 1], y1);
            }
            {
                const float dA = exp2f(d * a2[q * 4 + 2]);
                h[q * 4 + 2] = fmaf(dA, h[q * 4 + 2], dxv * Bv[q * 4 + 2]);
                y2 = fmaf(h[q * 4 + 2], Cv[q * 4 + 2], y2);
            }
            {
                const float dA = exp2f(d * a2[q * 4 + 3]);
                h[q * 4 + 3] = fmaf(dA, h[q * 4 + 3], dxv * Bv[q * 4 + 3]);
                y3 = fmaf(h[q * 4 + 3], Cv[q * 4 + 3], y3);
            }
        }
        const float y = (y0 + y1) + (y2 + y3);
        const float zs = zv / (1.f + expf(-zv));
        yg[r * DI + c] = __float2bfloat16((y + dp * xv) * zs);
    }
}

// ---------------------------------------------------------------------------
// One Mamba layer (8 dispatches)
// ---------------------------------------------------------------------------
static void run_mamba_layer(hipStream_t stream, float* resid,
                            const float* ln_w, const float* ln_b,
                            const bf16* inw_bf,
                            const float* conv_w, const float* conv_b,
                            const bf16* xpw_bf,
                            const float* dtw_t, const float* dt_b,
                            const float* Alog, const float* Dp,
                            const bf16* outw_bf,
                            bf16* ln_bf, bf16* xzb, bf16* xc_bf, float* dbc,
                            float* psum, float* ssum, bf16* yg_bf) {
    // LN (wave-per-row) -> bf16; also zeroes dbc for the split-K xp-GEMM
    ln_kernel<bf16><<<MR_ROWS / 4, 256, 0, stream>>>(resid, ln_w, ln_b, ln_bf, dbc);
    // xz = ln_out @ in_w^T : M=2048, N=2048, K=512, 128x128 tiles (m97 struct)
    gemm_bt<128, 128, 64, 4><<<dim3(2 * DI / 128, MR_ROWS / 128), 256, 0, stream>>>(
        ln_bf, DM, inw_bf, DM, (float*)xzb, 2 * DI, DM, nullptr);
    // conv+silu -> xc_bf (vectorized x8)
    conv_silu_b<<<MR_ROWS * DI / (256 * 8), 256, 0, stream>>>(xzb, conv_w, conv_b, xc_bf);
    // dbc = xc @ xp_w^T : split-K x4 -> 256 blocks
    gemm_bt<32, 64, 64, 2><<<dim3(1, MR_ROWS / 32, 4), 256, 0, stream>>>(
        xc_bf, DI, xpw_bf, DI, dbc, 64, DI / 4, nullptr);
    // 3-kernel chunked scan (dt projection fused, no delta buffer)
    scan_part1<<<dim3(DI / 64, NCHUNK / 4, LB), 256, 0, stream>>>(
        xc_bf, dbc, Alog, dtw_t, dt_b, psum, ssum);
    scan_combine<<<dim3(DI / 64, (LB * DSN) / 4), 256, 0, stream>>>(psum, ssum);
    scan_part3<<<dim3(DI / 64, NCHUNK / 4, LB), 256, 0, stream>>>(
        xc_bf, xzb, dbc, Alog, dtw_t, dt_b, Dp, psum, yg_bf);
    // resid += yg @ out_w^T : M=2048, N=512, K=1024 (64x64 -> 256 blocks)
    gemm_bt<64, 64, 64, 3><<<dim3(DM / 64, MR_ROWS / 64), 256, 0, stream>>>(
        yg_bf, DI, outw_bf, DI, resid, DM, DI, nullptr);
}

// ---------------------------------------------------------------------------
extern "C" void kernel_launch(void* const* d_in, const int* in_sizes, int n_in,
                              void* d_out, int out_size, void* d_ws, size_t ws_size,
                              hipStream_t stream) {
    const float* x         = (const float*)d_in[0];
    const float* inp_w     = (const float*)d_in[1];
    const float* inp_b     = (const float*)d_in[2];
    const float* enc_ln_w  = (const float*)d_in[3];
    const float* enc_ln_b  = (const float*)d_in[4];
    const float* enc_in_w  = (const float*)d_in[5];
    const float* enc_conv_w= (const float*)d_in[6];
    const float* enc_conv_b= (const float*)d_in[7];
    const float* enc_xp_w  = (const float*)d_in[8];
    const float* enc_dt_w  = (const float*)d_in[9];
    const float* enc_dt_b  = (const float*)d_in[10];
    const float* enc_Alog  = (const float*)d_in[11];
    const float* enc_D     = (const float*)d_in[12];
    const float* enc_out_w = (const float*)d_in[13];
    const float* fin_ln_w  = (const float*)d_in[14];
    const float* fin_ln_b  = (const float*)d_in[15];
    const float* prd_ln_w  = (const float*)d_in[16];
    const float* prd_ln_b  = (const float*)d_in[17];
    const float* prd_in_w  = (const float*)d_in[18];
    const float* prd_conv_w= (const float*)d_in[19];
    const float* prd_conv_b= (const float*)d_in[20];
    const float* prd_xp_w  = (const float*)d_in[21];
    const float* prd_dt_w  = (const float*)d_in[22];
    const float* prd_dt_b  = (const float*)d_in[23];
    const float* prd_Alog  = (const float*)d_in[24];
    const float* prd_D     = (const float*)d_in[25];
    const float* prd_out_w = (const float*)d_in[26];
    const float* prd_nrm_w = (const float*)d_in[27];
    const float* prd_nrm_b = (const float*)d_in[28];
    const float* prd_proj_w= (const float*)d_in[29];
    const float* prd_proj_b= (const float*)d_in[30];

    char* wp = (char*)d_ws;
    auto carve = [&](size_t elems, size_t esz) {
        void* p = (void*)wp;
        wp += (elems * esz + 255) & ~(size_t)255;
        return p;
    };
    bf16* x_bf     = (bf16*)carve((size_t)MR_ROWS * 128, 2);
    bf16* inpw_bf  = (bf16*)carve((size_t)DM * 128, 2);
    bf16* einw_bf  = (bf16*)carve(4ull * 2 * DI * DM, 2);
    bf16* expw_bf  = (bf16*)carve(4ull * 64 * DI, 2);
    bf16* eoutw_bf = (bf16*)carve(4ull * DM * DI, 2);
    bf16* pinw_bf  = (bf16*)carve(2ull * 2 * DI * DM, 2);
    bf16* pxpw_bf  = (bf16*)carve(2ull * 64 * DI, 2);
    bf16* poutw_bf = (bf16*)carve(2ull * DM * DI, 2);
    bf16* projw_bf = (bf16*)carve((size_t)DM * DM, 2);
    float* dtwt    = (float*)carve(6ull * RK * DI, 4);
    float* hbuf    = (float*)carve((size_t)MR_ROWS * DM, 4);
    float* pbuf    = (float*)carve((size_t)MR_ROWS * DM, 4);
    bf16* ln_bf    = (bf16*)carve((size_t)MR_ROWS * DM, 2);
    bf16* xzb      = (bf16*)carve((size_t)MR_ROWS * 2 * DI, 2);
    bf16* xc_bf    = (bf16*)carve((size_t)MR_ROWS * DI, 2);
    float* dbc     = (float*)carve((size_t)MR_ROWS * 64, 4);
    float* psum    = (float*)carve((size_t)LB * NCHUNK * DSN * DI, 4);
    float* ssum    = (float*)carve((size_t)LB * NCHUNK * DSN * DI, 4);
    bf16* yg_bf    = (bf16*)carve((size_t)MR_ROWS * DI, 2);

    // --- weight/input conversion to bf16 (one launch) + dtw transpose ---
    ConvArgs ca;
    const float* csrc[9] = {x, inp_w, enc_in_w, enc_xp_w, enc_out_w,
                            prd_in_w, prd_xp_w, prd_out_w, prd_proj_w};
    bf16* cdst[9] = {x_bf, inpw_bf, einw_bf, expw_bf, eoutw_bf,
                     pinw_bf, pxpw_bf, poutw_bf, projw_bf};
    const int cn[9] = {MR_ROWS * 128, DM * 128, 4 * 2 * DI * DM, 4 * 64 * DI, 4 * DM * DI,
                       2 * 2 * DI * DM, 2 * 64 * DI, 2 * DM * DI, DM * DM};
    for (int i = 0; i < 9; ++i) { ca.src[i] = csrc[i]; ca.dst[i] = cdst[i]; ca.n4[i] = cn[i] / 4; }
    convert_bf16_multi<<<dim3(128, 9), 256, 0, stream>>>(ca);
    transpose_dtw<<<dim3(RK * DI / 256, 6), 256, 0, stream>>>(enc_dt_w, prd_dt_w, dtwt);

    // --- input projection: h = x @ inp_w^T + inp_b  (M=2048, N=512, K=128) ---
    gemm_bt<64, 64, 64, 1><<<dim3(DM / 64, MR_ROWS / 64), 256, 0, stream>>>(
        x_bf, 128, inpw_bf, 128, hbuf, DM, 128, inp_b);

    // --- encoder layers ---
    for (int i = 0; i < 4; ++i) {
        run_mamba_layer(stream, hbuf,
                        enc_ln_w + (size_t)i * DM, enc_ln_b + (size_t)i * DM,
                        einw_bf + (size_t)i * 2 * DI * DM,
                        enc_conv_w + (size_t)i * DI * 4, enc_conv_b + (size_t)i * DI,
                        expw_bf + (size_t)i * 64 * DI,
                        dtwt + (size_t)i * RK * DI, enc_dt_b + (size_t)i * DI,
                        enc_Alog + (size_t)i * DI * DSN, enc_D + (size_t)i * DI,
                        eoutw_bf + (size_t)i * DM * DI,
                        ln_bf, xzb, xc_bf, dbc, psum, ssum, yg_bf);
    }

    // --- final encoder LN -> predictor stream ---
    ln_kernel<float><<<MR_ROWS / 4, 256, 0, stream>>>(hbuf, fin_ln_w, fin_ln_b, pbuf, nullptr);

    // --- predictor layers ---
    for (int i = 0; i < 2; ++i) {
        run_mamba_layer(stream, pbuf,
                        prd_ln_w + (size_t)i * DM, prd_ln_b + (size_t)i * DM,
                        pinw_bf + (size_t)i * 2 * DI * DM,
                        prd_conv_w + (size_t)i * DI * 4, prd_conv_b + (size_t)i * DI,
                        pxpw_bf + (size_t)i * 64 * DI,
                        dtwt + (size_t)(4 + i) * RK * DI, prd_dt_b + (size_t)i * DI,
                        prd_Alog + (size_t)i * DI * DSN, prd_D + (size_t)i * DI,
                        poutw_bf + (size_t)i * DM * DI,
                        ln_bf, xzb, xc_bf, dbc, psum, ssum, yg_bf);
    }

    // --- final norm + projection ---
    ln_kernel<bf16><<<MR_ROWS / 4, 256, 0, stream>>>(pbuf, prd_nrm_w, prd_nrm_b, ln_bf, nullptr);
    gemm_bt<64, 64, 64, 1><<<dim3(DM / 64, MR_ROWS / 64), 256, 0, stream>>>(
        ln_bf, DM, projw_bf, DM, (float*)d_out, DM, DM, prd_proj_b);

    (void)in_sizes; (void)n_in; (void)out_size; (void)ws_size;
}

// Round 12
// 622.701 us; speedup vs baseline: 3.2862x; 1.1143x over previous
//
#include <hip/hip_runtime.h>
#include <hip/hip_bf16.h>

using bf16 = __hip_bfloat16;
typedef __attribute__((ext_vector_type(8))) short short8;
typedef __attribute__((ext_vector_type(4))) float f32x4;

// Problem constants
static constexpr int LB = 2;           // batch
static constexpr int LL = 1024;        // seq len
static constexpr int DM = 512;         // d_model
static constexpr int DI = 1024;        // d_inner
static constexpr int DSN = 16;         // d_state
static constexpr int RK = 32;          // dt_rank
static constexpr int MR_ROWS = LB * LL; // 2048 rows

static constexpr int NCHUNK = 64;      // time chunks per sequence
static constexpr int CH = LL / NCHUNK; // 16 steps per chunk

// ---------------------------------------------------------------------------
// async global->LDS, 16B per lane. LDS dest is wave-uniform base + lane*16.
// ---------------------------------------------------------------------------
__device__ __forceinline__ void gload16(const void* g, void* l) {
    __builtin_amdgcn_global_load_lds(
        (__attribute__((address_space(1))) void*)(g),
        (__attribute__((address_space(3))) void*)(l), 16, 0, 0);
}

__device__ __forceinline__ float b2f(short v) {
    union { unsigned int u; float f; } cvt;
    cvt.u = ((unsigned int)(unsigned short)v) << 16;
    return cvt.f;
}

// ---------------------------------------------------------------------------
// fp32 -> bf16 conversion, multi-segment in one launch
// ---------------------------------------------------------------------------
struct ConvArgs {
    const float* src[9];
    bf16*        dst[9];
    int          n4[9];
};

__global__ __launch_bounds__(256) void convert_bf16_multi(ConvArgs a) {
    const int s = blockIdx.y;
    const float4* __restrict__ src = (const float4*)a.src[s];
    bf16* __restrict__ dst = a.dst[s];
    const int n4 = a.n4[s];
    for (int i = blockIdx.x * 256 + threadIdx.x; i < n4; i += gridDim.x * 256) {
        float4 v = src[i];
        bf16 t[4] = {__float2bfloat16(v.x), __float2bfloat16(v.y),
                     __float2bfloat16(v.z), __float2bfloat16(v.w)};
        *(uint2*)(dst + (size_t)i * 4) = *(uint2*)t;
    }
}

// ---------------------------------------------------------------------------
// dtw transpose: out[layer][k][c] = in[layer][c][k]  (fp32, one-time, small)
// ---------------------------------------------------------------------------
__global__ __launch_bounds__(256) void transpose_dtw(const float* __restrict__ enc_dtw,
                                                     const float* __restrict__ prd_dtw,
                                                     float* __restrict__ out) {
    const int layer = blockIdx.y;
    const float* src = (layer < 4) ? enc_dtw + (size_t)layer * DI * RK
                                   : prd_dtw + (size_t)(layer - 4) * DI * RK;
    float* dst = out + (size_t)layer * RK * DI;
    const int idx = blockIdx.x * 256 + threadIdx.x; // over RK*DI
    const int k = idx >> 10, c = idx & (DI - 1);
    dst[idx] = src[(size_t)c * RK + k];
}

// ---------------------------------------------------------------------------
// LayerNorm over last dim (512). Wave-per-row: block = 4 waves = 4 rows,
// grid 512. Wave-local shuffle reduce only. Optionally zeroes dbc.
// ---------------------------------------------------------------------------
__device__ __forceinline__ void ln_store8(float* outrow, int lane,
                                          const float* v) {
    float4 a = {v[0], v[1], v[2], v[3]}, b = {v[4], v[5], v[6], v[7]};
    ((float4*)outrow)[lane] = a;
    ((float4*)outrow)[lane + 64] = b;
}
__device__ __forceinline__ void ln_store8(bf16* outrow, int lane,
                                          const float* v) {
    bf16 t0[4] = {__float2bfloat16(v[0]), __float2bfloat16(v[1]),
                  __float2bfloat16(v[2]), __float2bfloat16(v[3])};
    bf16 t1[4] = {__float2bfloat16(v[4]), __float2bfloat16(v[5]),
                  __float2bfloat16(v[6]), __float2bfloat16(v[7])};
    ((uint2*)outrow)[lane] = *(uint2*)t0;
    ((uint2*)outrow)[lane + 64] = *(uint2*)t1;
}

template <typename T>
__global__ __launch_bounds__(256) void ln_kernel(const float* __restrict__ x,
                                                 const float* __restrict__ w,
                                                 const float* __restrict__ b,
                                                 T* __restrict__ out,
                                                 float* __restrict__ dbc_zero) {
    if (dbc_zero != nullptr && blockIdx.x < 128) {
        ((float4*)dbc_zero)[blockIdx.x * 256 + threadIdx.x] =
            make_float4(0.f, 0.f, 0.f, 0.f);
    }
    const int wid = threadIdx.x >> 6, lane = threadIdx.x & 63;
    const int row = blockIdx.x * 4 + wid;
    const float4* xr = (const float4*)(x + (size_t)row * DM);
    const float4 v0 = xr[lane], v1 = xr[lane + 64];

    float s = (v0.x + v0.y + v0.z + v0.w) + (v1.x + v1.y + v1.z + v1.w);
#pragma unroll
    for (int m = 1; m < 64; m <<= 1) s += __shfl_xor(s, m);
    const float mean = s * (1.f / DM);

    float d[8] = {v0.x - mean, v0.y - mean, v0.z - mean, v0.w - mean,
                  v1.x - mean, v1.y - mean, v1.z - mean, v1.w - mean};
    float s2 = 0.f;
#pragma unroll
    for (int q = 0; q < 8; ++q) s2 += d[q] * d[q];
#pragma unroll
    for (int m = 1; m < 64; m <<= 1) s2 += __shfl_xor(s2, m);
    const float rs = rsqrtf(s2 * (1.f / DM) + 1e-5f);

    const float4 w0 = ((const float4*)w)[lane], w1 = ((const float4*)w)[lane + 64];
    const float4 b0 = ((const float4*)b)[lane], b1 = ((const float4*)b)[lane + 64];
    float o[8] = {d[0] * rs * w0.x + b0.x, d[1] * rs * w0.y + b0.y,
                  d[2] * rs * w0.z + b0.z, d[3] * rs * w0.w + b0.w,
                  d[4] * rs * w1.x + b1.x, d[5] * rs * w1.y + b1.y,
                  d[6] * rs * w1.z + b1.z, d[7] * rs * w1.w + b1.w};
    ln_store8(out + (size_t)row * DM, lane, o);
}

// ---------------------------------------------------------------------------
// GEMM: C[M,N] = A[M,K] * B[N,K]^T  (A,B bf16 row-major K-contiguous)
// EPI: 1 = +bias[col] (fp32 C), 2 = atomicAdd split-K over blockIdx.z
//      (K arg = per-chunk K), 3 = += existing C (residual), 4 = bf16 C out.
// Staging via global_load_lds(16B): linear LDS dest, PRE-SWIZZLED global
// source; swizzled ds_read (rule #21).
// ---------------------------------------------------------------------------
template <int BM, int BN, int BK, int EPI>
__global__ __launch_bounds__(256) void gemm_bt(const bf16* __restrict__ A, int lda,
                                               const bf16* __restrict__ B, int ldb,
                                               float* __restrict__ C, int ldc,
                                               int K, const float* __restrict__ bias) {
    static_assert(BK == 64, "layout assumes 128B LDS row");
    static_assert(BM % 32 == 0 && BN % 32 == 0, "wave staging granularity");
    constexpr int MR = (BM / 2) / 16;
    constexpr int NR = (BN / 2) / 16;
    __shared__ __align__(16) char sA[BM * 128];
    __shared__ __align__(16) char sB[BN * 128];

    const int tid = threadIdx.x;
    const int lane = tid & 63, wid = tid >> 6;
    const int wr = wid >> 1, wc = wid & 1;
    const int m0 = blockIdx.y * BM, n0 = blockIdx.x * BN;
    const int kbase = (EPI == 2) ? blockIdx.z * K : 0;

    f32x4 acc[MR][NR] = {};

    // per-lane staging source (pre-swizzled)
    const int lrow = lane >> 3;               // 0..7
    const int lcol = (lane & 7) ^ lrow;       // swizzled 16B block
    const size_t lda2 = (size_t)lda * 2, ldb2 = (size_t)ldb * 2;
    const char* Ab = (const char*)A + (size_t)(m0 + wid * (BM / 4) + lrow) * lda2
                     + lcol * 16 + (size_t)kbase * 2;
    const char* Bb = (const char*)B + (size_t)(n0 + wid * (BN / 4) + lrow) * ldb2
                     + lcol * 16 + (size_t)kbase * 2;
    char* sAw = sA + wid * (BM / 4) * 128;
    char* sBw = sB + wid * (BN / 4) * 128;

    for (int k0 = 0; k0 < K; k0 += BK) {
#pragma unroll
        for (int i = 0; i < BM / 32; ++i)
            gload16(Ab + (size_t)i * 8 * lda2 + (size_t)k0 * 2, sAw + i * 1024);
#pragma unroll
        for (int i = 0; i < BN / 32; ++i)
            gload16(Bb + (size_t)i * 8 * ldb2 + (size_t)k0 * 2, sBw + i * 1024);
        __syncthreads();
#pragma unroll
        for (int kk = 0; kk < BK; kk += 32) {
            const int kb2 = (kk + (lane >> 4) * 8) * 2; // byte col, 16B aligned
            short8 af[MR], bfr[NR];
#pragma unroll
            for (int m = 0; m < MR; ++m) {
                const int r = wr * (BM / 2) + m * 16 + (lane & 15);
                af[m] = *(const short8*)(sA + r * 128 + (kb2 ^ ((r & 7) << 4)));
            }
#pragma unroll
            for (int n = 0; n < NR; ++n) {
                const int r = wc * (BN / 2) + n * 16 + (lane & 15);
                bfr[n] = *(const short8*)(sB + r * 128 + (kb2 ^ ((r & 7) << 4)));
            }
#pragma unroll
            for (int m = 0; m < MR; ++m) {
#pragma unroll
                for (int n = 0; n < NR; ++n) {
                    acc[m][n] = __builtin_amdgcn_mfma_f32_16x16x32_bf16(af[m], bfr[n], acc[m][n], 0, 0, 0);
                }
            }
        }
        __syncthreads();
    }

#pragma unroll
    for (int m = 0; m < MR; ++m) {
#pragma unroll
        for (int n = 0; n < NR; ++n) {
            const int col = n0 + wc * (BN / 2) + n * 16 + (lane & 15);
            const float bv = (EPI == 1) ? bias[col] : 0.f;
#pragma unroll
            for (int j = 0; j < 4; ++j) {
                const int row = m0 + wr * (BM / 2) + m * 16 + (lane >> 4) * 4 + j;
                float v = acc[m][n][j] + bv;
                if (EPI == 4) {
                    ((bf16*)C)[(size_t)row * ldc + col] = __float2bfloat16(v);
                } else {
                    float* p = C + (size_t)row * ldc + col;
                    if (EPI == 2) {
                        atomicAdd(p, v);
                    } else {
                        if (EPI == 3) v += *p;
                        *p = v;
                    }
                }
            }
        }
    }
}

// ---------------------------------------------------------------------------
// Causal depthwise conv (K=4) + SiLU, bf16 in/out, vectorized 8 ch/thread.
// ---------------------------------------------------------------------------
__global__ __launch_bounds__(256) void conv_silu_b(const bf16* __restrict__ xzb,
                                                   const float* __restrict__ cw,
                                                   const float* __restrict__ cb,
                                                   bf16* __restrict__ xc_bf) {
    const int idx = blockIdx.x * 256 + threadIdx.x; // over 2048*128 groups
    const int c8 = (idx & 127) * 8;
    const int r = idx >> 7;
    const int l = r & (LL - 1);
    const bf16* xi = xzb + (size_t)r * (2 * DI) + c8;
    const short8 zv8 = {};
    const short8 x0 = *(const short8*)xi;
    const short8 x1 = (l >= 1) ? *(const short8*)(xi - 2 * DI) : zv8;
    const short8 x2 = (l >= 2) ? *(const short8*)(xi - 4 * DI) : zv8;
    const short8 x3 = (l >= 3) ? *(const short8*)(xi - 6 * DI) : zv8;

    bf16 outv[8];
#pragma unroll
    for (int j = 0; j < 8; ++j) {
        const float4 w = *(const float4*)(cw + (size_t)(c8 + j) * 4);
        float acc = cb[c8 + j] + w.w * b2f(x0[j]) + w.z * b2f(x1[j])
                    + w.y * b2f(x2[j]) + w.x * b2f(x3[j]);
        const float s = acc / (1.f + expf(-acc)); // silu
        outv[j] = __float2bfloat16(s);
    }
    *(uint4*)(xc_bf + (size_t)r * DI + c8) = *(uint4*)outv;
}

// ---------------------------------------------------------------------------
// Selective scan, 3-kernel chunked form; channel in the LANE dimension.
// part1 computes delta = softplus(dt @ dt_w^T + dt_b) inline AND STORES it;
// part3 just reads it (drops the wv[32] register array -> higher occupancy).
// ---------------------------------------------------------------------------
__global__ __launch_bounds__(256) void scan_part1(const bf16* __restrict__ xcb,
                                                  const float* __restrict__ dbc,
                                                  const float* __restrict__ Alog,
                                                  const float* __restrict__ dtw_t,
                                                  const float* __restrict__ dtb,
                                                  float* __restrict__ delta,
                                                  float* __restrict__ psum,
                                                  float* __restrict__ ssum) {
    const int lane = threadIdx.x & 63;
    const int wsub = threadIdx.x >> 6;
    const int c = blockIdx.x * 64 + lane;
    const int chunk = blockIdx.y * 4 + wsub;
    const int b = blockIdx.z;
    const int r0 = b * LL + chunk * CH;

    float wv[RK];
#pragma unroll
    for (int k = 0; k < RK; ++k) wv[k] = dtw_t[(size_t)k * DI + c];
    const float bdt = dtb[c];

    float a2[DSN];
#pragma unroll
    for (int q = 0; q < 4; ++q) {
        const float4 al = *(const float4*)(Alog + (size_t)c * DSN + q * 4);
        a2[q * 4 + 0] = -expf(al.x) * 1.44269504f;
        a2[q * 4 + 1] = -expf(al.y) * 1.44269504f;
        a2[q * 4 + 2] = -expf(al.z) * 1.44269504f;
        a2[q * 4 + 3] = -expf(al.w) * 1.44269504f;
    }

    float h[DSN], P[DSN];
#pragma unroll
    for (int n = 0; n < DSN; ++n) { h[n] = 0.f; P[n] = 1.f; }

    for (int t = 0; t < CH; ++t) {
        const size_t r = r0 + t;
        float acc = bdt;
#pragma unroll
        for (int q = 0; q < RK / 4; ++q) {
            const float4 d4 = *(const float4*)(dbc + r * 64 + q * 4);
            acc = fmaf(d4.x, wv[q * 4 + 0], acc);
            acc = fmaf(d4.y, wv[q * 4 + 1], acc);
            acc = fmaf(d4.z, wv[q * 4 + 2], acc);
            acc = fmaf(d4.w, wv[q * 4 + 3], acc);
        }
        const float d = (acc > 20.f) ? acc : log1pf(expf(acc));
        delta[r * DI + c] = d;

        const float xv = __bfloat162float(xcb[r * DI + c]);
        const float dxv = d * xv;
        float Bv[DSN];
#pragma unroll
        for (int q = 0; q < 4; ++q)
            *(float4*)&Bv[q * 4] = *(const float4*)(dbc + r * 64 + 32 + q * 4);
#pragma unroll
        for (int n = 0; n < DSN; ++n) {
            const float dA = exp2f(d * a2[n]);
            h[n] = fmaf(dA, h[n], dxv * Bv[n]);
            P[n] *= dA;
        }
    }

    const size_t obase = ((size_t)(b * NCHUNK + chunk) * DSN) * DI + c;
#pragma unroll
    for (int n = 0; n < DSN; ++n) {
        psum[obase + (size_t)n * DI] = P[n];
        ssum[obase + (size_t)n * DI] = h[n];
    }
}

__global__ __launch_bounds__(256) void scan_combine(float* __restrict__ psum,
                                                    const float* __restrict__ ssum) {
    const int lane = threadIdx.x & 63;
    const int idx = blockIdx.y * 4 + (threadIdx.x >> 6); // [0,32): b*16+n
    const int b = idx >> 4, n = idx & 15;
    const int c = blockIdx.x * 64 + lane;
    const size_t base = ((size_t)(b * NCHUNK) * DSN + n) * DI + c;
    const size_t stride = (size_t)DSN * DI; // chunk stride

    float h = 0.f;
    for (int j0 = 0; j0 < NCHUNK; j0 += 8) {
        float Pv[8], Sv[8];
#pragma unroll
        for (int u = 0; u < 8; ++u) {
            Pv[u] = psum[base + (j0 + u) * stride];
            Sv[u] = ssum[base + (j0 + u) * stride];
        }
#pragma unroll
        for (int u = 0; u < 8; ++u) {
            psum[base + (j0 + u) * stride] = h; // h_in for chunk j0+u
            h = fmaf(Pv[u], h, Sv[u]);
        }
    }
}

__global__ __launch_bounds__(256) void scan_part3(const bf16* __restrict__ xcb,
                                                  const bf16* __restrict__ xzb,
                                                  const float* __restrict__ dbc,
                                                  const float* __restrict__ Alog,
                                                  const float* __restrict__ delta,
                                                  const float* __restrict__ Dp,
                                                  const float* __restrict__ hin,
                                                  bf16* __restrict__ yg) {
    const int lane = threadIdx.x & 63;
    const int wsub = threadIdx.x >> 6;
    const int c = blockIdx.x * 64 + lane;
    const int chunk = blockIdx.y * 4 + wsub;
    const int b = blockIdx.z;
    const int r0 = b * LL + chunk * CH;

    float a2[DSN];
#pragma unroll
    for (int q = 0; q < 4; ++q) {
        const float4 al = *(const float4*)(Alog + (size_t)c * DSN + q * 4);
        a2[q * 4 + 0] = -expf(al.x) * 1.44269504f;
        a2[q * 4 + 1] = -expf(al.y) * 1.44269504f;
        a2[q * 4 + 2] = -expf(al.z) * 1.44269504f;
        a2[q * 4 + 3] = -expf(al.w) * 1.44269504f;
    }
    const float dp = Dp[c];

    float h[DSN];
    const size_t hbase = ((size_t)(b * NCHUNK + chunk) * DSN) * DI + c;
#pragma unroll
    for (int n = 0; n < DSN; ++n) h[n] = hin[hbase + (size_t)n * DI];

    for (int t = 0; t < CH; ++t) {
        const size_t r = r0 + t;
        const float d = delta[r * DI + c];
        const float xv = __bfloat162float(xcb[r * DI + c]);
        const float zv = __bfloat162float(xzb[r * (2 * DI) + DI + c]);
        const float dxv = d * xv;
        float Bv[DSN], Cv[DSN];
#pragma unroll
        for (int q = 0; q < 4; ++q) {
            *(float4*)&Bv[q * 4] = *(const float4*)(dbc + r * 64 + 32 + q * 4);
            *(float4*)&Cv[q * 4] = *(const float4*)(dbc + r * 64 + 48 + q * 4);
        }
        float y0 = 0.f, y1 = 0.f, y2 = 0.f, y3 = 0.f;
#pragma unroll
        for (int q = 0; q < 4; ++q) {
            {
                const float dA = exp2f(d * a2[q * 4 + 0]);
                h[q * 4 + 0] = fmaf(dA, h[q * 4 + 0], dxv * Bv[q * 4 + 0]);
                y0 = fmaf(h[q * 4 + 0], Cv[q * 4 + 0], y0);
            }
            {
                const float dA = exp2f(d * a2[q * 4 + 1]);
                h[q * 4 + 1] = fmaf(dA, h[q * 4 + 1], dxv * Bv[q * 4 + 1]);
                y1 = fmaf(h[q * 4 + 1], Cv[q * 4 + 1], y1);
            }
            {
                const float dA = exp2f(d * a2[q * 4 + 2]);
                h[q * 4 + 2] = fmaf(dA, h[q * 4 + 2], dxv * Bv[q * 4 + 2]);
                y2 = fmaf(h[q * 4 + 2], Cv[q * 4 + 2], y2);
            }
            {
                const float dA = exp2f(d * a2[q * 4 + 3]);
                h[q * 4 + 3] = fmaf(dA, h[q * 4 + 3], dxv * Bv[q * 4 + 3]);
                y3 = fmaf(h[q * 4 + 3], Cv[q * 4 + 3], y3);
            }
        }
        const float y = (y0 + y1) + (y2 + y3);
        const float zs = zv / (1.f + expf(-zv));
        yg[r * DI + c] = __float2bfloat16((y + dp * xv) * zs);
    }
}

// ---------------------------------------------------------------------------
// One Mamba layer (8 dispatches)
// ---------------------------------------------------------------------------
static void run_mamba_layer(hipStream_t stream, float* resid,
                            const float* ln_w, const float* ln_b,
                            const bf16* inw_bf,
                            const float* conv_w, const float* conv_b,
                            const bf16* xpw_bf,
                            const float* dtw_t, const float* dt_b,
                            const float* Alog, const float* Dp,
                            const bf16* outw_bf,
                            bf16* ln_bf, bf16* xzb, bf16* xc_bf, float* dbc,
                            float* delta, float* psum, float* ssum, bf16* yg_bf) {
    // LN (wave-per-row) -> bf16; also zeroes dbc for the split-K xp-GEMM
    ln_kernel<bf16><<<MR_ROWS / 4, 256, 0, stream>>>(resid, ln_w, ln_b, ln_bf, dbc);
    // xz = ln_out @ in_w^T : M=2048, N=2048, K=512, 64x64 tiles (1024 blocks)
    gemm_bt<64, 64, 64, 4><<<dim3(2 * DI / 64, MR_ROWS / 64), 256, 0, stream>>>(
        ln_bf, DM, inw_bf, DM, (float*)xzb, 2 * DI, DM, nullptr);
    // conv+silu -> xc_bf (vectorized x8)
    conv_silu_b<<<MR_ROWS * DI / (256 * 8), 256, 0, stream>>>(xzb, conv_w, conv_b, xc_bf);
    // dbc = xc @ xp_w^T : split-K x4 -> 256 blocks
    gemm_bt<32, 64, 64, 2><<<dim3(1, MR_ROWS / 32, 4), 256, 0, stream>>>(
        xc_bf, DI, xpw_bf, DI, dbc, 64, DI / 4, nullptr);
    // 3-kernel chunked scan (dt projection in part1, delta stored for part3)
    scan_part1<<<dim3(DI / 64, NCHUNK / 4, LB), 256, 0, stream>>>(
        xc_bf, dbc, Alog, dtw_t, dt_b, delta, psum, ssum);
    scan_combine<<<dim3(DI / 64, (LB * DSN) / 4), 256, 0, stream>>>(psum, ssum);
    scan_part3<<<dim3(DI / 64, NCHUNK / 4, LB), 256, 0, stream>>>(
        xc_bf, xzb, dbc, Alog, delta, Dp, psum, yg_bf);
    // resid += yg @ out_w^T : M=2048, N=512, K=1024 (32x64 -> 512 blocks)
    gemm_bt<32, 64, 64, 3><<<dim3(DM / 64, MR_ROWS / 32), 256, 0, stream>>>(
        yg_bf, DI, outw_bf, DI, resid, DM, DI, nullptr);
}

// ---------------------------------------------------------------------------
extern "C" void kernel_launch(void* const* d_in, const int* in_sizes, int n_in,
                              void* d_out, int out_size, void* d_ws, size_t ws_size,
                              hipStream_t stream) {
    const float* x         = (const float*)d_in[0];
    const float* inp_w     = (const float*)d_in[1];
    const float* inp_b     = (const float*)d_in[2];
    const float* enc_ln_w  = (const float*)d_in[3];
    const float* enc_ln_b  = (const float*)d_in[4];
    const float* enc_in_w  = (const float*)d_in[5];
    const float* enc_conv_w= (const float*)d_in[6];
    const float* enc_conv_b= (const float*)d_in[7];
    const float* enc_xp_w  = (const float*)d_in[8];
    const float* enc_dt_w  = (const float*)d_in[9];
    const float* enc_dt_b  = (const float*)d_in[10];
    const float* enc_Alog  = (const float*)d_in[11];
    const float* enc_D     = (const float*)d_in[12];
    const float* enc_out_w = (const float*)d_in[13];
    const float* fin_ln_w  = (const float*)d_in[14];
    const float* fin_ln_b  = (const float*)d_in[15];
    const float* prd_ln_w  = (const float*)d_in[16];
    const float* prd_ln_b  = (const float*)d_in[17];
    const float* prd_in_w  = (const float*)d_in[18];
    const float* prd_conv_w= (const float*)d_in[19];
    const float* prd_conv_b= (const float*)d_in[20];
    const float* prd_xp_w  = (const float*)d_in[21];
    const float* prd_dt_w  = (const float*)d_in[22];
    const float* prd_dt_b  = (const float*)d_in[23];
    const float* prd_Alog  = (const float*)d_in[24];
    const float* prd_D     = (const float*)d_in[25];
    const float* prd_out_w = (const float*)d_in[26];
    const float* prd_nrm_w = (const float*)d_in[27];
    const float* prd_nrm_b = (const float*)d_in[28];
    const float* prd_proj_w= (const float*)d_in[29];
    const float* prd_proj_b= (const float*)d_in[30];

    char* wp = (char*)d_ws;
    auto carve = [&](size_t elems, size_t esz) {
        void* p = (void*)wp;
        wp += (elems * esz + 255) & ~(size_t)255;
        return p;
    };
    bf16* x_bf     = (bf16*)carve((size_t)MR_ROWS * 128, 2);
    bf16* inpw_bf  = (bf16*)carve((size_t)DM * 128, 2);
    bf16* einw_bf  = (bf16*)carve(4ull * 2 * DI * DM, 2);
    bf16* expw_bf  = (bf16*)carve(4ull * 64 * DI, 2);
    bf16* eoutw_bf = (bf16*)carve(4ull * DM * DI, 2);
    bf16* pinw_bf  = (bf16*)carve(2ull * 2 * DI * DM, 2);
    bf16* pxpw_bf  = (bf16*)carve(2ull * 64 * DI, 2);
    bf16* poutw_bf = (bf16*)carve(2ull * DM * DI, 2);
    bf16* projw_bf = (bf16*)carve((size_t)DM * DM, 2);
    float* dtwt    = (float*)carve(6ull * RK * DI, 4);
    float* hbuf    = (float*)carve((size_t)MR_ROWS * DM, 4);
    float* pbuf    = (float*)carve((size_t)MR_ROWS * DM, 4);
    bf16* ln_bf    = (bf16*)carve((size_t)MR_ROWS * DM, 2);
    bf16* xzb      = (bf16*)carve((size_t)MR_ROWS * 2 * DI, 2);
    bf16* xc_bf    = (bf16*)carve((size_t)MR_ROWS * DI, 2);
    float* dbc     = (float*)carve((size_t)MR_ROWS * 64, 4);
    float* delta   = (float*)carve((size_t)MR_ROWS * DI, 4);
    float* psum    = (float*)carve((size_t)LB * NCHUNK * DSN * DI, 4);
    float* ssum    = (float*)carve((size_t)LB * NCHUNK * DSN * DI, 4);
    bf16* yg_bf    = (bf16*)carve((size_t)MR_ROWS * DI, 2);

    // --- weight/input conversion to bf16 (one launch) + dtw transpose ---
    ConvArgs ca;
    const float* csrc[9] = {x, inp_w, enc_in_w, enc_xp_w, enc_out_w,
                            prd_in_w, prd_xp_w, prd_out_w, prd_proj_w};
    bf16* cdst[9] = {x_bf, inpw_bf, einw_bf, expw_bf, eoutw_bf,
                     pinw_bf, pxpw_bf, poutw_bf, projw_bf};
    const int cn[9] = {MR_ROWS * 128, DM * 128, 4 * 2 * DI * DM, 4 * 64 * DI, 4 * DM * DI,
                       2 * 2 * DI * DM, 2 * 64 * DI, 2 * DM * DI, DM * DM};
    for (int i = 0; i < 9; ++i) { ca.src[i] = csrc[i]; ca.dst[i] = cdst[i]; ca.n4[i] = cn[i] / 4; }
    convert_bf16_multi<<<dim3(128, 9), 256, 0, stream>>>(ca);
    transpose_dtw<<<dim3(RK * DI / 256, 6), 256, 0, stream>>>(enc_dt_w, prd_dt_w, dtwt);

    // --- input projection: h = x @ inp_w^T + inp_b  (M=2048, N=512, K=128) ---
    gemm_bt<32, 64, 64, 1><<<dim3(DM / 64, MR_ROWS / 32), 256, 0, stream>>>(
        x_bf, 128, inpw_bf, 128, hbuf, DM, 128, inp_b);

    // --- encoder layers ---
    for (int i = 0; i < 4; ++i) {
        run_mamba_layer(stream, hbuf,
                        enc_ln_w + (size_t)i * DM, enc_ln_b + (size_t)i * DM,
                        einw_bf + (size_t)i * 2 * DI * DM,
                        enc_conv_w + (size_t)i * DI * 4, enc_conv_b + (size_t)i * DI,
                        expw_bf + (size_t)i * 64 * DI,
                        dtwt + (size_t)i * RK * DI, enc_dt_b + (size_t)i * DI,
                        enc_Alog + (size_t)i * DI * DSN, enc_D + (size_t)i * DI,
                        eoutw_bf + (size_t)i * DM * DI,
                        ln_bf, xzb, xc_bf, dbc, delta, psum, ssum, yg_bf);
    }

    // --- final encoder LN -> predictor stream ---
    ln_kernel<float><<<MR_ROWS / 4, 256, 0, stream>>>(hbuf, fin_ln_w, fin_ln_b, pbuf, nullptr);

    // --- predictor layers ---
    for (int i = 0; i < 2; ++i) {
        run_mamba_layer(stream, pbuf,
                        prd_ln_w + (size_t)i * DM, prd_ln_b + (size_t)i * DM,
                        pinw_bf + (size_t)i * 2 * DI * DM,
                        prd_conv_w + (size_t)i * DI * 4, prd_conv_b + (size_t)i * DI,
                        pxpw_bf + (size_t)i * 64 * DI,
                        dtwt + (size_t)(4 + i) * RK * DI, prd_dt_b + (size_t)i * DI,
                        prd_Alog + (size_t)i * DI * DSN, prd_D + (size_t)i * DI,
                        poutw_bf + (size_t)i * DM * DI,
                        ln_bf, xzb, xc_bf, dbc, delta, psum, ssum, yg_bf);
    }

    // --- final norm + projection ---
    ln_kernel<bf16><<<MR_ROWS / 4, 256, 0, stream>>>(pbuf, prd_nrm_w, prd_nrm_b, ln_bf, nullptr);
    gemm_bt<32, 64, 64, 1><<<dim3(DM / 64, MR_ROWS / 32), 256, 0, stream>>>(
        ln_bf, DM, projw_bf, DM, (float*)d_out, DM, DM, prd_proj_b);

    (void)in_sizes; (void)n_in; (void)out_size; (void)ws_size;
}